// Round 14
// baseline (1682.414 us; speedup 1.0000x reference)
//
#include <hip/hip_runtime.h>

#define B 128
#define T 1500
#define NI 80        // N_MELS
#define H 128        // HIDDEN
#define G 384        // 3*H
#define GT 64        // gemm g-tile
#define NTT 128      // gemm t-tile

typedef float v2f __attribute__((ext_vector_type(2)));

__device__ __forceinline__ float sigf(float x) { return 1.0f / (1.0f + __expf(-x)); }
__device__ __forceinline__ float tanhfast(float x) { return 1.0f - 2.0f / (1.0f + __expf(2.0f * x)); }
__device__ __forceinline__ v2f pkfma(v2f a, v2f b, v2f c) { return __builtin_elementwise_fma(a, b, c); }

// AGPR pin: write once (opaque asm def -> cannot be rematerialized), read full-rate.
__device__ __forceinline__ float awrite(float v) {
    float a;
    asm volatile("v_accvgpr_write_b32 %0, %1" : "=a"(a) : "v"(v));
    return a;
}
__device__ __forceinline__ float aread(float a) {
    float v;
    asm volatile("v_accvgpr_read_b32 %0, %1" : "=v"(v) : "a"(a));
    return v;
}

// butterfly sum over lanes xor1 + xor2 via DPP quad_perm (VALU pipe)
__device__ __forceinline__ float qsum(float v) {
    int a = __builtin_bit_cast(int, v);
    int b = __builtin_amdgcn_update_dpp(0, a, 0xB1, 0xF, 0xF, true);   // [1,0,3,2]
    float s = v + __builtin_bit_cast(float, b);
    int c = __builtin_bit_cast(int, s);
    int d = __builtin_amdgcn_update_dpp(0, c, 0x4E, 0xF, 0xF, true);   // [2,3,0,1]
    return s + __builtin_bit_cast(float, d);
}

// ---------------- gx GEMM v2: tiled, LDS-staged, writes TRANSPOSED gxT[b][g][t] ----------------
__global__ __launch_bounds__(256, 2)
void gx_gemm_kernel(const float* __restrict__ x, const float* __restrict__ w_ih,
                    const float* __restrict__ b_ih, float* __restrict__ gxT,
                    int t0, int ct) {
    __shared__ __align__(16) float wT[80][GT + 2];    // 66 stride
    __shared__ __align__(16) float xT[80][NTT + 4];   // 132 stride
    __shared__ float bias_s[GT];
    int tid = threadIdx.x;
    int b = blockIdx.z;
    int g0b = blockIdx.y * GT;
    int tt0 = blockIdx.x * NTT;

    for (int i = tid; i < GT * 20; i += 256) {
        int g = i & (GT - 1);
        int kc = i >> 6;
        float4 v = *(const float4*)(w_ih + (size_t)(g0b + g) * NI + 4 * kc);
        wT[4 * kc + 0][g] = v.x; wT[4 * kc + 1][g] = v.y;
        wT[4 * kc + 2][g] = v.z; wT[4 * kc + 3][g] = v.w;
    }
    for (int i = tid; i < NTT * 20; i += 256) {
        int c = i & (NTT - 1);
        int kc = i >> 7;
        int tt = tt0 + c; if (tt > ct - 1) tt = ct - 1;
        float4 v = *(const float4*)(x + ((size_t)b * T + (size_t)(t0 + tt)) * NI + 4 * kc);
        xT[4 * kc + 0][c] = v.x; xT[4 * kc + 1][c] = v.y;
        xT[4 * kc + 2][c] = v.z; xT[4 * kc + 3][c] = v.w;
    }
    if (tid < GT) bias_s[tid] = b_ih[g0b + tid];
    __syncthreads();

    int gi = tid & 15;   // 4g block
    int ti = tid >> 4;   // 8t block
    v2f acc[4][4];
#pragma unroll
    for (int r = 0; r < 4; ++r)
#pragma unroll
        for (int j = 0; j < 4; ++j) acc[r][j] = v2f{0.f, 0.f};

#pragma unroll 2
    for (int k = 0; k < 80; ++k) {
        const v2f* wv = (const v2f*)&wT[k][4 * gi];
        v2f w01 = wv[0], w23 = wv[1];
        const float4* xv = (const float4*)&xT[k][8 * ti];
        float4 x03 = xv[0], x47 = xv[1];
        v2f xp0 = {x03.x, x03.y}, xp1 = {x03.z, x03.w};
        v2f xp2 = {x47.x, x47.y}, xp3 = {x47.z, x47.w};
        float wr[4] = {w01.x, w01.y, w23.x, w23.y};
#pragma unroll
        for (int r = 0; r < 4; ++r) {
            v2f ws = {wr[r], wr[r]};
            acc[r][0] = pkfma(ws, xp0, acc[r][0]);
            acc[r][1] = pkfma(ws, xp1, acc[r][1]);
            acc[r][2] = pkfma(ws, xp2, acc[r][2]);
            acc[r][3] = pkfma(ws, xp3, acc[r][3]);
        }
    }

#pragma unroll
    for (int r = 0; r < 4; ++r) {
        int g = g0b + 4 * gi + r;
        float bias = bias_s[4 * gi + r];
        float* orow = gxT + ((size_t)b * G + g) * ct + tt0 + 8 * ti;
#pragma unroll
        for (int j = 0; j < 4; ++j) {
            int t = tt0 + 8 * ti + 2 * j;
            if (t < ct) {
                float2 o; o.x = acc[r][j].x + bias; o.y = acc[r][j].y + bias;
                *(float2*)(orow + 2 * j) = o;
            }
        }
    }
}

// ---------------- scan: W_hh pinned in AGPRs ----------------
// 128 blocks x 512 threads. tid = j*4 + q, j in [0,128), q in [0,4). Thread owns
// W_hh rows {j, j+H, j+2H}, k-slice [32q,32q+32) = 96 floats, pinned in AGPRs via
// v_accvgpr_write (asm defs cannot be rematerialized -> no per-step global W
// reloads, the invariant ~900cyc/step stall of r4-r13). Per step: 8 ds_read_b128
// (h slice, bank-exact 36-float q-stride), 96 accvgpr_read + 96 fmaf (3 chains),
// 2-level DPP qsum, gates on all lanes, q==0 writes h. gx transposed float4
// prefetch (distance 8) and raw s_barrier + lgkmcnt-only wait from r10.
__global__ __launch_bounds__(512)
__attribute__((amdgpu_waves_per_eu(2, 2)))
void scan_kernel(const float* __restrict__ gxT, const float* __restrict__ w_hh,
                 const float* __restrict__ b_hh, float* __restrict__ h_state,
                 int ct, int first, int last,
                 const float* __restrict__ x,
                 const float* __restrict__ w_ih_b, const float* __restrict__ b_ih_b,
                 const float* __restrict__ b_hh_b,
                 const float* __restrict__ w1, const float* __restrict__ b1,
                 const float* __restrict__ w2, const float* __restrict__ b2,
                 float* __restrict__ out) {
    int b = blockIdx.x;
    int tid = threadIdx.x;
    int j = tid >> 2;         // 0..127
    int q = tid & 3;          // 0..3
    int jpad = j + ((j >> 5) << 2);   // padded h index (36-float q-slice stride)
    bool writer = (q == 0);

    __shared__ __align__(16) float hs[2][144];
    __shared__ __align__(16) float tail_gx[G];
    __shared__ __align__(16) float last_s[2 * H];
    __shared__ __align__(16) float xb_s[NI];

    // Load W_hh rows {j, j+H, j+2H} slice [32q,32q+32), pin all 96 floats in AGPRs.
    float AW[96];
    {
        const float* wb = w_hh + 32 * q;
        const float4* p0 = (const float4*)(wb + (size_t)j * H);
        const float4* p1 = (const float4*)(wb + (size_t)(j + H) * H);
        const float4* p2 = (const float4*)(wb + (size_t)(j + 2 * H) * H);
#pragma unroll
        for (int i = 0; i < 8; ++i) {
            float4 vr = p0[i], vz = p1[i], vn = p2[i];
            AW[4 * i + 0]      = awrite(vr.x); AW[4 * i + 1]      = awrite(vr.y);
            AW[4 * i + 2]      = awrite(vr.z); AW[4 * i + 3]      = awrite(vr.w);
            AW[32 + 4 * i + 0] = awrite(vz.x); AW[32 + 4 * i + 1] = awrite(vz.y);
            AW[32 + 4 * i + 2] = awrite(vz.z); AW[32 + 4 * i + 3] = awrite(vz.w);
            AW[64 + 4 * i + 0] = awrite(vn.x); AW[64 + 4 * i + 1] = awrite(vn.y);
            AW[64 + 4 * i + 2] = awrite(vn.z); AW[64 + 4 * i + 3] = awrite(vn.w);
        }
    }
    float br = b_hh[j], bz = b_hh[j + H], bn = b_hh[j + 2 * H];

    float h_cur = 0.f;
    if (!first) h_cur = h_state[b * H + j];
    if (writer) hs[0][jpad] = h_cur;

    // transposed-gx row pointers for this thread's 3 gate rows
    const float* gp0 = gxT + ((size_t)b * G + j) * ct;
    const float* gp1 = gp0 + (size_t)H * ct;
    const float* gp2 = gp0 + (size_t)(2 * H) * ct;

    // two float4 sets, each covering 4 steps; prefetch distance = 8 steps
    float4 A0, A1, A2, B0, B1, B2;
    A0 = *(const float4*)(gp0); A1 = *(const float4*)(gp1); A2 = *(const float4*)(gp2);
    {
        int t4 = (ct - 4 < 4) ? (ct - 4) : 4;
        B0 = *(const float4*)(gp0 + t4); B1 = *(const float4*)(gp1 + t4); B2 = *(const float4*)(gp2 + t4);
    }
    __syncthreads();   // prologue only

    auto dostep = [&](float g0, float g1, float g2, const float* SRC, float* DST) {
        const float4* hv4 = (const float4*)(SRC + 36 * q);
        float ar = 0.f, az = 0.f, an = 0.f;
#pragma unroll
        for (int i = 0; i < 8; ++i) {
            float4 hv = hv4[i];
            ar = fmaf(aread(AW[4 * i + 0]), hv.x, ar);
            ar = fmaf(aread(AW[4 * i + 1]), hv.y, ar);
            ar = fmaf(aread(AW[4 * i + 2]), hv.z, ar);
            ar = fmaf(aread(AW[4 * i + 3]), hv.w, ar);
            az = fmaf(aread(AW[32 + 4 * i + 0]), hv.x, az);
            az = fmaf(aread(AW[32 + 4 * i + 1]), hv.y, az);
            az = fmaf(aread(AW[32 + 4 * i + 2]), hv.z, az);
            az = fmaf(aread(AW[32 + 4 * i + 3]), hv.w, az);
            an = fmaf(aread(AW[64 + 4 * i + 0]), hv.x, an);
            an = fmaf(aread(AW[64 + 4 * i + 1]), hv.y, an);
            an = fmaf(aread(AW[64 + 4 * i + 2]), hv.z, an);
            an = fmaf(aread(AW[64 + 4 * i + 3]), hv.w, an);
        }
        ar = qsum(ar); az = qsum(az); an = qsum(an);
        float r = sigf(g0 + br + ar);
        float z = sigf(g1 + bz + az);
        float n = tanhfast(g2 + r * (bn + an));
        h_cur = n + z * (h_cur - n);
        if (writer) DST[jpad] = h_cur;
        asm volatile("s_waitcnt lgkmcnt(0)\n\ts_barrier" ::: "memory");
    };

    auto superstep = [&](int TL, float4& S0, float4& S1, float4& S2) {
        float l00 = S0.x, l01 = S0.y, l02 = S0.z, l03 = S0.w;
        float l10 = S1.x, l11 = S1.y, l12 = S1.z, l13 = S1.w;
        float l20 = S2.x, l21 = S2.y, l22 = S2.z, l23 = S2.w;
        int tpf = TL + 8; if (tpf > ct - 4) tpf = ct - 4;
        S0 = *(const float4*)(gp0 + tpf);
        S1 = *(const float4*)(gp1 + tpf);
        S2 = *(const float4*)(gp2 + tpf);
        dostep(l00, l10, l20, hs[0], hs[1]);
        dostep(l01, l11, l21, hs[1], hs[0]);
        dostep(l02, l12, l22, hs[0], hs[1]);
        dostep(l03, l13, l23, hs[1], hs[0]);
    };

    int tl = 0;
    for (; tl + 8 <= ct; tl += 8) {
        superstep(tl, A0, A1, A2);
        superstep(tl + 4, B0, B1, B2);
    }
    if (tl < ct) superstep(tl, A0, A1, A2);   // ct is a multiple of 4

    if (!last) {
        if (writer) h_state[b * H + j] = h_cur;
        return;
    }

    // ---- backward single step (h0 = 0) + MLP head ----
    if (tid < NI) xb_s[tid] = x[((size_t)b * T + (T - 1)) * NI + tid];
    if (writer) last_s[j] = h_cur;  // forward final hidden
    __syncthreads();

    if (tid < G) {
        const float4* wbr = (const float4*)(w_ih_b + (size_t)tid * NI);
        const float4* xv = (const float4*)xb_s;
        float a0 = 0.f, a1 = 0.f, a2 = 0.f, a3 = 0.f;
#pragma unroll
        for (int i = 0; i < 20; ++i) {
            float4 wv = wbr[i]; float4 x4 = xv[i];
            a0 = fmaf(wv.x, x4.x, a0); a1 = fmaf(wv.y, x4.y, a1);
            a2 = fmaf(wv.z, x4.z, a2); a3 = fmaf(wv.w, x4.w, a3);
        }
        tail_gx[tid] = b_ih_b[tid] + ((a0 + a1) + (a2 + a3));
    }
    __syncthreads();

    if (tid < H) {
        float r = sigf(tail_gx[tid] + b_hh_b[tid]);
        float z = sigf(tail_gx[tid + H] + b_hh_b[tid + H]);
        float n = tanhfast(tail_gx[tid + 2 * H] + r * b_hh_b[tid + 2 * H]);
        last_s[H + tid] = (1.f - z) * n;  // + z*0
    }
    __syncthreads();

    if (tid < 64) {
        const float4* w1r = (const float4*)(w1 + (size_t)tid * 2 * H);
        const float4* lv = (const float4*)last_s;
        float a0 = 0.f, a1 = 0.f, a2 = 0.f, a3 = 0.f;
#pragma unroll
        for (int i = 0; i < 64; ++i) {
            float4 wv = w1r[i]; float4 l4 = lv[i];
            a0 = fmaf(wv.x, l4.x, a0); a1 = fmaf(wv.y, l4.y, a1);
            a2 = fmaf(wv.z, l4.z, a2); a3 = fmaf(wv.w, l4.w, a3);
        }
        float v = b1[tid] + ((a0 + a1) + (a2 + a3));
        v = fmaxf(v, 0.f) * w2[tid];
#pragma unroll
        for (int off = 32; off > 0; off >>= 1) v += __shfl_down(v, off);
        if (tid == 0) out[b] = v + b2[0];
    }
}

extern "C" void kernel_launch(void* const* d_in, const int* in_sizes, int n_in,
                              void* d_out, int out_size, void* d_ws, size_t ws_size,
                              hipStream_t stream) {
    (void)in_sizes; (void)n_in; (void)out_size;
    const float* x      = (const float*)d_in[0];
    const float* w_ih_f = (const float*)d_in[1];
    const float* w_hh_f = (const float*)d_in[2];
    const float* b_ih_f = (const float*)d_in[3];
    const float* b_hh_f = (const float*)d_in[4];
    const float* w_ih_b = (const float*)d_in[5];
    const float* w_hh_b = (const float*)d_in[6];  // unused: h0=0 makes gh_b = b_hh_b
    const float* b_ih_b = (const float*)d_in[7];
    const float* b_hh_b = (const float*)d_in[8];
    const float* w1     = (const float*)d_in[9];
    const float* b1     = (const float*)d_in[10];
    const float* w2     = (const float*)d_in[11];
    const float* b2     = (const float*)d_in[12];
    (void)w_hh_b;
    float* out = (float*)d_out;

    float* h_state = (float*)d_ws;                 // B*H floats
    float* gxbuf = h_state + B * H;
    size_t hbytes = (size_t)B * H * sizeof(float);
    size_t avail = ws_size > hbytes ? ws_size - hbytes : 0;
    long long chunkT = (long long)(avail / ((size_t)B * G * sizeof(float)));
    chunkT &= ~3LL;                                // multiple of 4 (float4 gx path)
    if (chunkT > T) chunkT = T;
    if (chunkT < 4) chunkT = 4;

    for (int t0 = 0; t0 < T; t0 += (int)chunkT) {
        int ct = (T - t0 < (int)chunkT) ? (T - t0) : (int)chunkT;
        int ttiles = (ct + NTT - 1) / NTT;
        gx_gemm_kernel<<<dim3(ttiles, G / GT, B), dim3(256), 0, stream>>>(
            x, w_ih_f, b_ih_f, gxbuf, t0, ct);
        scan_kernel<<<dim3(B), dim3(512), 0, stream>>>(
            gxbuf, w_hh_f, b_hh_f, h_state, ct,
            (t0 == 0) ? 1 : 0, (t0 + ct >= T) ? 1 : 0,
            x, w_ih_b, b_ih_b, b_hh_b, w1, b1, w2, b2, out);
    }
}

// Round 16
// 1117.967 us; speedup vs baseline: 1.5049x; 1.5049x over previous
//
#include <hip/hip_runtime.h>

#define B 128
#define T 1500
#define NI 80        // N_MELS
#define H 128        // HIDDEN
#define G 384        // 3*H
#define GT 64        // gemm g-tile
#define NTT 128      // gemm t-tile

typedef float v2f __attribute__((ext_vector_type(2)));

__device__ __forceinline__ float sigf(float x) { return 1.0f / (1.0f + __expf(-x)); }
__device__ __forceinline__ float tanhfast(float x) { return 1.0f - 2.0f / (1.0f + __expf(2.0f * x)); }
__device__ __forceinline__ v2f pkfma(v2f a, v2f b, v2f c) { return __builtin_elementwise_fma(a, b, c); }

// sum over an aligned 8-lane group, entirely on the VALU pipe (DPP):
// half_mirror (i<->7-i), quad reverse [3,2,1,0], quad xor1 [1,0,3,2]
__device__ __forceinline__ float sum8(float v) {
    int a = __builtin_bit_cast(int, v);
    float m = __builtin_bit_cast(float, __builtin_amdgcn_update_dpp(0, a, 0x141, 0xF, 0xF, true)); // half_mirror
    float s = v + m;
    a = __builtin_bit_cast(int, s);
    m = __builtin_bit_cast(float, __builtin_amdgcn_update_dpp(0, a, 0x1B, 0xF, 0xF, true));  // quad rev
    s = s + m;
    a = __builtin_bit_cast(int, s);
    m = __builtin_bit_cast(float, __builtin_amdgcn_update_dpp(0, a, 0xB1, 0xF, 0xF, true));  // quad xor1
    return s + m;
}

// ---------------- gx GEMM v3: v2 compute + LDS-staged coalesced output ----------------
// v2's transposed global stores scattered 8B/lane across 16 g-rows -> 2-4x write
// amplification on a 295MB stream. v3 stages the 64x128 output tile in LDS (reusing
// xT, stride 132 = 16B-aligned rows) and copies out with consecutive-lane float4
// stores (fully coalesced). Compute structure unchanged from v2.
__global__ __launch_bounds__(256, 2)
void gx_gemm_kernel(const float* __restrict__ x, const float* __restrict__ w_ih,
                    const float* __restrict__ b_ih, float* __restrict__ gxT,
                    int t0, int ct) {
    __shared__ __align__(16) float wT[80][GT + 2];    // 66 stride
    __shared__ __align__(16) float xT[80][NTT + 4];   // 132 stride; reused as out-tile
    __shared__ float bias_s[GT];
    int tid = threadIdx.x;
    int b = blockIdx.z;
    int g0b = blockIdx.y * GT;
    int tt0 = blockIdx.x * NTT;

    for (int i = tid; i < GT * 20; i += 256) {
        int g = i & (GT - 1);
        int kc = i >> 6;
        float4 v = *(const float4*)(w_ih + (size_t)(g0b + g) * NI + 4 * kc);
        wT[4 * kc + 0][g] = v.x; wT[4 * kc + 1][g] = v.y;
        wT[4 * kc + 2][g] = v.z; wT[4 * kc + 3][g] = v.w;
    }
    for (int i = tid; i < NTT * 20; i += 256) {
        int c = i & (NTT - 1);
        int kc = i >> 7;
        int tt = tt0 + c; if (tt > ct - 1) tt = ct - 1;
        float4 v = *(const float4*)(x + ((size_t)b * T + (size_t)(t0 + tt)) * NI + 4 * kc);
        xT[4 * kc + 0][c] = v.x; xT[4 * kc + 1][c] = v.y;
        xT[4 * kc + 2][c] = v.z; xT[4 * kc + 3][c] = v.w;
    }
    if (tid < GT) bias_s[tid] = b_ih[g0b + tid];
    __syncthreads();

    int gi = tid & 15;   // 4g block
    int ti = tid >> 4;   // 8t block
    v2f acc[4][4];
#pragma unroll
    for (int r = 0; r < 4; ++r)
#pragma unroll
        for (int j = 0; j < 4; ++j) acc[r][j] = v2f{0.f, 0.f};

#pragma unroll 2
    for (int k = 0; k < 80; ++k) {
        const v2f* wv = (const v2f*)&wT[k][4 * gi];
        v2f w01 = wv[0], w23 = wv[1];
        const float4* xv = (const float4*)&xT[k][8 * ti];
        float4 x03 = xv[0], x47 = xv[1];
        v2f xp0 = {x03.x, x03.y}, xp1 = {x03.z, x03.w};
        v2f xp2 = {x47.x, x47.y}, xp3 = {x47.z, x47.w};
        float wr[4] = {w01.x, w01.y, w23.x, w23.y};
#pragma unroll
        for (int r = 0; r < 4; ++r) {
            v2f ws = {wr[r], wr[r]};
            acc[r][0] = pkfma(ws, xp0, acc[r][0]);
            acc[r][1] = pkfma(ws, xp1, acc[r][1]);
            acc[r][2] = pkfma(ws, xp2, acc[r][2]);
            acc[r][3] = pkfma(ws, xp3, acc[r][3]);
        }
    }
    __syncthreads();   // all xT reads done; reuse as output tile

    float (*ot)[NTT + 4] = (float (*)[NTT + 4])xT;   // 64 rows x 132, 16B-aligned rows
#pragma unroll
    for (int r = 0; r < 4; ++r) {
        float bias = bias_s[4 * gi + r];
#pragma unroll
        for (int j = 0; j < 4; ++j) {
            float2 o; o.x = acc[r][j].x + bias; o.y = acc[r][j].y + bias;
            *(float2*)&ot[4 * gi + r][8 * ti + 2 * j] = o;
        }
    }
    __syncthreads();

    // coalesced copy-out: 2048 float4, consecutive threads -> consecutive 16B in row
    for (int i = tid; i < GT * (NTT / 4); i += 256) {
        int row = i >> 5;          // /32 float4 per row
        int col = i & 31;
        int t = tt0 + 4 * col;
        if (t < ct) {
            float4 v = *(const float4*)&ot[row][4 * col];
            *(float4*)(gxT + ((size_t)b * G + g0b + row) * ct + t) = v;
        }
    }
}

// ---------------- scan (TRUE r13 scan: sum8 8-lane reduce; proven 852us, absmax 0) ----------------
// 128 blocks x 512 threads. tid = jp*8 + q, jp in [0,64), q in [0,8).
// Thread accumulates 6 partial dots (j=jp and j=jp+64, gates r/z/n) over k-slice
// [16q,16q+16): 4 ds_read_b128 per step. 8-lane butterfly reduce via sum8 (DPP).
// Lanes q<4 finalize gates for jp, q>=4 for jp+64. h slices padded to 20 floats.
// gx transposed float4 prefetch (distance 8); raw s_barrier + lgkmcnt-only wait.
__global__ __launch_bounds__(512)
__attribute__((amdgpu_waves_per_eu(2, 2)))
void scan_kernel(const float* __restrict__ gxT, const float* __restrict__ w_hh,
                 const float* __restrict__ b_hh, float* __restrict__ h_state,
                 int ct, int first, int last,
                 const float* __restrict__ x,
                 const float* __restrict__ w_ih_b, const float* __restrict__ b_ih_b,
                 const float* __restrict__ b_hh_b,
                 const float* __restrict__ w1, const float* __restrict__ b1,
                 const float* __restrict__ w2, const float* __restrict__ b2,
                 float* __restrict__ out) {
    int b = blockIdx.x;
    int tid = threadIdx.x;
    int jp = tid >> 3;        // 0..63
    int q = tid & 7;          // 0..7
    int j0 = jp, j1 = jp + 64;
    int jsel = (q < 4) ? j0 : j1;
    int hsel = ((jsel >> 4) * 20) + (jsel & 15);   // padded LDS index of h[jsel]
    bool writer = (q & 3) == 0;                    // q==0 writes j0, q==4 writes j1

    __shared__ __align__(16) float hs[2][160];     // 8 slices x 20 floats (bank-exact)
    __shared__ __align__(16) float tail_gx[G];
    __shared__ __align__(16) float last_s[2 * H];
    __shared__ __align__(16) float xb_s[NI];

    // W_hh fragments as v2f: rows {j0, j0+H, j0+2H, j1, j1+H, j1+2H}, k in [16q,16q+16)
    v2f W0r[8], W0z[8], W0n[8], W1r[8], W1z[8], W1n[8];
    {
        const float* wb = w_hh + 16 * q;
        const v2f* p0 = (const v2f*)(wb + (size_t)j0 * H);
        const v2f* p1 = (const v2f*)(wb + (size_t)(j0 + H) * H);
        const v2f* p2 = (const v2f*)(wb + (size_t)(j0 + 2 * H) * H);
        const v2f* p3 = (const v2f*)(wb + (size_t)j1 * H);
        const v2f* p4 = (const v2f*)(wb + (size_t)(j1 + H) * H);
        const v2f* p5 = (const v2f*)(wb + (size_t)(j1 + 2 * H) * H);
#pragma unroll
        for (int i = 0; i < 8; ++i) {
            W0r[i] = p0[i]; W0z[i] = p1[i]; W0n[i] = p2[i];
            W1r[i] = p3[i]; W1z[i] = p4[i]; W1n[i] = p5[i];
        }
    }
#pragma unroll
    for (int i = 0; i < 8; ++i) {
        asm volatile("" : "+v"(W0r[i]), "+v"(W0z[i]), "+v"(W0n[i]),
                          "+v"(W1r[i]), "+v"(W1z[i]), "+v"(W1n[i]));
    }
    float br = b_hh[jsel], bz = b_hh[jsel + H], bn = b_hh[jsel + 2 * H];

    float h_cur = 0.f;
    if (!first) h_cur = h_state[b * H + jsel];
    if (writer) hs[0][hsel] = h_cur;

    const float* gp0 = gxT + ((size_t)b * G + jsel) * ct;
    const float* gp1 = gp0 + (size_t)H * ct;
    const float* gp2 = gp0 + (size_t)(2 * H) * ct;

    float4 A0, A1, A2, B0, B1, B2;
    A0 = *(const float4*)(gp0); A1 = *(const float4*)(gp1); A2 = *(const float4*)(gp2);
    {
        int t4 = (ct - 4 < 4) ? (ct - 4) : 4;
        B0 = *(const float4*)(gp0 + t4); B1 = *(const float4*)(gp1 + t4); B2 = *(const float4*)(gp2 + t4);
    }
    __syncthreads();   // prologue only

    auto dostep = [&](float g0, float g1, float g2, const float* SRC, float* DST) {
        const float4* hv4 = (const float4*)(SRC + 20 * q);
        float4 h0 = hv4[0], h1 = hv4[1], h2 = hv4[2], h3 = hv4[3];
        v2f a0r = {0.f, 0.f}, a0z = {0.f, 0.f}, a0n = {0.f, 0.f};
        v2f a1r = {0.f, 0.f}, a1z = {0.f, 0.f}, a1n = {0.f, 0.f};
        float4 hh[4] = {h0, h1, h2, h3};
#pragma unroll
        for (int i = 0; i < 4; ++i) {
            v2f hl = {hh[i].x, hh[i].y}, hg = {hh[i].z, hh[i].w};
            a0r = pkfma(W0r[2 * i], hl, a0r); a0r = pkfma(W0r[2 * i + 1], hg, a0r);
            a0z = pkfma(W0z[2 * i], hl, a0z); a0z = pkfma(W0z[2 * i + 1], hg, a0z);
            a0n = pkfma(W0n[2 * i], hl, a0n); a0n = pkfma(W0n[2 * i + 1], hg, a0n);
            a1r = pkfma(W1r[2 * i], hl, a1r); a1r = pkfma(W1r[2 * i + 1], hg, a1r);
            a1z = pkfma(W1z[2 * i], hl, a1z); a1z = pkfma(W1z[2 * i + 1], hg, a1z);
            a1n = pkfma(W1n[2 * i], hl, a1n); a1n = pkfma(W1n[2 * i + 1], hg, a1n);
        }
        float s0r = sum8(a0r.x + a0r.y), s0z = sum8(a0z.x + a0z.y), s0n = sum8(a0n.x + a0n.y);
        float s1r = sum8(a1r.x + a1r.y), s1z = sum8(a1z.x + a1z.y), s1n = sum8(a1n.x + a1n.y);
        bool lo = q < 4;
        float ar = lo ? s0r : s1r;
        float az = lo ? s0z : s1z;
        float an = lo ? s0n : s1n;
        float r = sigf(g0 + br + ar);
        float z = sigf(g1 + bz + az);
        float n = tanhfast(g2 + r * (bn + an));
        h_cur = n + z * (h_cur - n);
        if (writer) DST[hsel] = h_cur;
        asm volatile("s_waitcnt lgkmcnt(0)\n\ts_barrier" ::: "memory");
    };

    auto superstep = [&](int TL, float4& S0, float4& S1, float4& S2) {
        float l00 = S0.x, l01 = S0.y, l02 = S0.z, l03 = S0.w;
        float l10 = S1.x, l11 = S1.y, l12 = S1.z, l13 = S1.w;
        float l20 = S2.x, l21 = S2.y, l22 = S2.z, l23 = S2.w;
        int tpf = TL + 8; if (tpf > ct - 4) tpf = ct - 4;
        S0 = *(const float4*)(gp0 + tpf);
        S1 = *(const float4*)(gp1 + tpf);
        S2 = *(const float4*)(gp2 + tpf);
        dostep(l00, l10, l20, hs[0], hs[1]);
        dostep(l01, l11, l21, hs[1], hs[0]);
        dostep(l02, l12, l22, hs[0], hs[1]);
        dostep(l03, l13, l23, hs[1], hs[0]);
    };

    int tl = 0;
    for (; tl + 8 <= ct; tl += 8) {
        superstep(tl, A0, A1, A2);
        superstep(tl + 4, B0, B1, B2);
    }
    if (tl < ct) superstep(tl, A0, A1, A2);   // ct is a multiple of 4

    if (!last) {
        if (writer) h_state[b * H + jsel] = h_cur;
        return;
    }

    // ---- backward single step (h0 = 0) + MLP head ----
    if (tid < NI) xb_s[tid] = x[((size_t)b * T + (T - 1)) * NI + tid];
    if (writer) last_s[jsel] = h_cur;  // forward final hidden
    __syncthreads();

    if (tid < G) {
        const float4* wbr = (const float4*)(w_ih_b + (size_t)tid * NI);
        const float4* xv = (const float4*)xb_s;
        float a0 = 0.f, a1 = 0.f, a2 = 0.f, a3 = 0.f;
#pragma unroll
        for (int i = 0; i < 20; ++i) {
            float4 wv = wbr[i]; float4 x4 = xv[i];
            a0 = fmaf(wv.x, x4.x, a0); a1 = fmaf(wv.y, x4.y, a1);
            a2 = fmaf(wv.z, x4.z, a2); a3 = fmaf(wv.w, x4.w, a3);
        }
        tail_gx[tid] = b_ih_b[tid] + ((a0 + a1) + (a2 + a3));
    }
    __syncthreads();

    if (tid < H) {
        float r = sigf(tail_gx[tid] + b_hh_b[tid]);
        float z = sigf(tail_gx[tid + H] + b_hh_b[tid + H]);
        float n = tanhfast(tail_gx[tid + 2 * H] + r * b_hh_b[tid + 2 * H]);
        last_s[H + tid] = (1.f - z) * n;  // + z*0
    }
    __syncthreads();

    if (tid < 64) {
        const float4* w1r = (const float4*)(w1 + (size_t)tid * 2 * H);
        const float4* lv = (const float4*)last_s;
        float a0 = 0.f, a1 = 0.f, a2 = 0.f, a3 = 0.f;
#pragma unroll
        for (int i = 0; i < 64; ++i) {
            float4 wv = w1r[i]; float4 l4 = lv[i];
            a0 = fmaf(wv.x, l4.x, a0); a1 = fmaf(wv.y, l4.y, a1);
            a2 = fmaf(wv.z, l4.z, a2); a3 = fmaf(wv.w, l4.w, a3);
        }
        float v = b1[tid] + ((a0 + a1) + (a2 + a3));
        v = fmaxf(v, 0.f) * w2[tid];
#pragma unroll
        for (int off = 32; off > 0; off >>= 1) v += __shfl_down(v, off);
        if (tid == 0) out[b] = v + b2[0];
    }
}

extern "C" void kernel_launch(void* const* d_in, const int* in_sizes, int n_in,
                              void* d_out, int out_size, void* d_ws, size_t ws_size,
                              hipStream_t stream) {
    (void)in_sizes; (void)n_in; (void)out_size;
    const float* x      = (const float*)d_in[0];
    const float* w_ih_f = (const float*)d_in[1];
    const float* w_hh_f = (const float*)d_in[2];
    const float* b_ih_f = (const float*)d_in[3];
    const float* b_hh_f = (const float*)d_in[4];
    const float* w_ih_b = (const float*)d_in[5];
    const float* w_hh_b = (const float*)d_in[6];  // unused: h0=0 makes gh_b = b_hh_b
    const float* b_ih_b = (const float*)d_in[7];
    const float* b_hh_b = (const float*)d_in[8];
    const float* w1     = (const float*)d_in[9];
    const float* b1     = (const float*)d_in[10];
    const float* w2     = (const float*)d_in[11];
    const float* b2     = (const float*)d_in[12];
    (void)w_hh_b;
    float* out = (float*)d_out;

    float* h_state = (float*)d_ws;                 // B*H floats
    float* gxbuf = h_state + B * H;
    size_t hbytes = (size_t)B * H * sizeof(float);
    size_t avail = ws_size > hbytes ? ws_size - hbytes : 0;
    long long chunkT = (long long)(avail / ((size_t)B * G * sizeof(float)));
    chunkT &= ~3LL;                                // multiple of 4 (float4 gx path)
    if (chunkT > T) chunkT = T;
    if (chunkT < 4) chunkT = 4;

    for (int t0 = 0; t0 < T; t0 += (int)chunkT) {
        int ct = (T - t0 < (int)chunkT) ? (T - t0) : (int)chunkT;
        int ttiles = (ct + NTT - 1) / NTT;
        gx_gemm_kernel<<<dim3(ttiles, G / GT, B), dim3(256), 0, stream>>>(
            x, w_ih_f, b_ih_f, gxbuf, t0, ct);
        scan_kernel<<<dim3(B), dim3(512), 0, stream>>>(
            gxbuf, w_hh_f, b_hh_f, h_state, ct,
            (t0 == 0) ? 1 : 0, (t0 + ct >= T) ? 1 : 0,
            x, w_ih_b, b_ih_b, b_hh_b, w1, b1, w2, b2, out);
    }
}

// Round 17
// 962.820 us; speedup vs baseline: 1.7474x; 1.1611x over previous
//
#include <hip/hip_runtime.h>

#define B 128
#define T 1500
#define NI 80        // N_MELS
#define H 128        // HIDDEN
#define G 384        // 3*H
#define GT 64        // gemm g-tile
#define NTT 128      // gemm t-tile

#define WSZ (80 * (GT + 2))     // 5280 floats, wT
#define XSZ (80 * (NTT + 4))    // 10560 floats, xT / out-tile
#define SMEM_FLOATS (WSZ + XSZ + GT)

typedef float v2f __attribute__((ext_vector_type(2)));

__device__ __forceinline__ float sigf(float x) { return 1.0f / (1.0f + __expf(-x)); }
__device__ __forceinline__ float tanhfast(float x) { return 1.0f - 2.0f / (1.0f + __expf(2.0f * x)); }
__device__ __forceinline__ v2f pkfma(v2f a, v2f b, v2f c) { return __builtin_elementwise_fma(a, b, c); }

// sum over an aligned 8-lane group, entirely on the VALU pipe (DPP):
// half_mirror (i<->7-i), quad reverse [3,2,1,0], quad xor1 [1,0,3,2]
__device__ __forceinline__ float sum8(float v) {
    int a = __builtin_bit_cast(int, v);
    float m = __builtin_bit_cast(float, __builtin_amdgcn_update_dpp(0, a, 0x141, 0xF, 0xF, true)); // half_mirror
    float s = v + m;
    a = __builtin_bit_cast(int, s);
    m = __builtin_bit_cast(float, __builtin_amdgcn_update_dpp(0, a, 0x1B, 0xF, 0xF, true));  // quad rev
    s = s + m;
    a = __builtin_bit_cast(int, s);
    m = __builtin_bit_cast(float, __builtin_amdgcn_update_dpp(0, a, 0xB1, 0xF, 0xF, true));  // quad xor1
    return s + m;
}

// Merged kernel: blocks [0, scanBlocks) run the scan for chunk i (gx_read, ct_read);
// blocks [scanBlocks, 256) run the gemm producing chunk i+1 (gx_write, ct_write).
// Roles touch disjoint buffers -> no intra-kernel dependency, no deadlock possible.
// waves_per_eu(2,2): 512 thr = 8 waves = exactly 2/EU -> 1 block/CU -> 256 blocks
// co-resident on 256 CUs; scan uses 128 CUs, gemm overlaps on the other 128.
__global__ __launch_bounds__(512)
__attribute__((amdgpu_waves_per_eu(2, 2)))
void fused_kernel(const float* __restrict__ x,
                  const float* __restrict__ w_ih, const float* __restrict__ b_ih,
                  const float* __restrict__ gx_read, int ct_read, int first, int last,
                  float* __restrict__ gx_write, int t0_write, int ct_write,
                  const float* __restrict__ w_hh, const float* __restrict__ b_hh,
                  float* __restrict__ h_state,
                  const float* __restrict__ w_ih_b, const float* __restrict__ b_ih_b,
                  const float* __restrict__ b_hh_b,
                  const float* __restrict__ w1, const float* __restrict__ b1,
                  const float* __restrict__ w2, const float* __restrict__ b2,
                  float* __restrict__ out) {
    __shared__ __align__(16) float smem[SMEM_FLOATS];   // ~63.6 KB, union of both roles
    int tid = threadIdx.x;
    int scanBlocks = (ct_read > 0) ? B : 0;

    if ((int)blockIdx.x < scanBlocks) {
        // ================= SCAN ROLE (r16-proven body; hs arrays -> smem overlays) ==========
        const float* gxT = gx_read;
        int ct = ct_read;
        int b = blockIdx.x;
        int jp = tid >> 3;        // 0..63
        int q = tid & 7;          // 0..7
        int j0 = jp, j1 = jp + 64;
        int jsel = (q < 4) ? j0 : j1;
        int hsel = ((jsel >> 4) * 20) + (jsel & 15);   // padded LDS index of h[jsel]
        bool writer = (q & 3) == 0;                    // q==0 writes j0, q==4 writes j1

        float* hsA     = smem;           // 160 floats (8 slices x 20, bank-exact)
        float* hsB     = smem + 160;     // 160
        float* tail_gx = smem + 320;     // 384
        float* last_s  = smem + 704;     // 256
        float* xb_s    = smem + 960;     // 80

        // W_hh fragments as v2f: rows {j0, j0+H, j0+2H, j1, j1+H, j1+2H}, k in [16q,16q+16)
        v2f W0r[8], W0z[8], W0n[8], W1r[8], W1z[8], W1n[8];
        {
            const float* wb = w_hh + 16 * q;
            const v2f* p0 = (const v2f*)(wb + (size_t)j0 * H);
            const v2f* p1 = (const v2f*)(wb + (size_t)(j0 + H) * H);
            const v2f* p2 = (const v2f*)(wb + (size_t)(j0 + 2 * H) * H);
            const v2f* p3 = (const v2f*)(wb + (size_t)j1 * H);
            const v2f* p4 = (const v2f*)(wb + (size_t)(j1 + H) * H);
            const v2f* p5 = (const v2f*)(wb + (size_t)(j1 + 2 * H) * H);
#pragma unroll
            for (int i = 0; i < 8; ++i) {
                W0r[i] = p0[i]; W0z[i] = p1[i]; W0n[i] = p2[i];
                W1r[i] = p3[i]; W1z[i] = p4[i]; W1n[i] = p5[i];
            }
        }
#pragma unroll
        for (int i = 0; i < 8; ++i) {
            asm volatile("" : "+v"(W0r[i]), "+v"(W0z[i]), "+v"(W0n[i]),
                              "+v"(W1r[i]), "+v"(W1z[i]), "+v"(W1n[i]));
        }
        float br = b_hh[jsel], bz = b_hh[jsel + H], bn = b_hh[jsel + 2 * H];

        float h_cur = 0.f;
        if (!first) h_cur = h_state[b * H + jsel];
        if (writer) hsA[hsel] = h_cur;

        const float* gp0 = gxT + ((size_t)b * G + jsel) * ct;
        const float* gp1 = gp0 + (size_t)H * ct;
        const float* gp2 = gp0 + (size_t)(2 * H) * ct;

        float4 A0, A1, A2, B0, B1, B2;
        A0 = *(const float4*)(gp0); A1 = *(const float4*)(gp1); A2 = *(const float4*)(gp2);
        {
            int t4 = (ct - 4 < 4) ? (ct - 4) : 4;
            B0 = *(const float4*)(gp0 + t4); B1 = *(const float4*)(gp1 + t4); B2 = *(const float4*)(gp2 + t4);
        }
        __syncthreads();   // prologue only

        auto dostep = [&](float g0, float g1, float g2, const float* SRC, float* DST) {
            const float4* hv4 = (const float4*)(SRC + 20 * q);
            float4 h0 = hv4[0], h1 = hv4[1], h2 = hv4[2], h3 = hv4[3];
            v2f a0r = {0.f, 0.f}, a0z = {0.f, 0.f}, a0n = {0.f, 0.f};
            v2f a1r = {0.f, 0.f}, a1z = {0.f, 0.f}, a1n = {0.f, 0.f};
            float4 hh[4] = {h0, h1, h2, h3};
#pragma unroll
            for (int i = 0; i < 4; ++i) {
                v2f hl = {hh[i].x, hh[i].y}, hg = {hh[i].z, hh[i].w};
                a0r = pkfma(W0r[2 * i], hl, a0r); a0r = pkfma(W0r[2 * i + 1], hg, a0r);
                a0z = pkfma(W0z[2 * i], hl, a0z); a0z = pkfma(W0z[2 * i + 1], hg, a0z);
                a0n = pkfma(W0n[2 * i], hl, a0n); a0n = pkfma(W0n[2 * i + 1], hg, a0n);
                a1r = pkfma(W1r[2 * i], hl, a1r); a1r = pkfma(W1r[2 * i + 1], hg, a1r);
                a1z = pkfma(W1z[2 * i], hl, a1z); a1z = pkfma(W1z[2 * i + 1], hg, a1z);
                a1n = pkfma(W1n[2 * i], hl, a1n); a1n = pkfma(W1n[2 * i + 1], hg, a1n);
            }
            float s0r = sum8(a0r.x + a0r.y), s0z = sum8(a0z.x + a0z.y), s0n = sum8(a0n.x + a0n.y);
            float s1r = sum8(a1r.x + a1r.y), s1z = sum8(a1z.x + a1z.y), s1n = sum8(a1n.x + a1n.y);
            bool lo = q < 4;
            float ar = lo ? s0r : s1r;
            float az = lo ? s0z : s1z;
            float an = lo ? s0n : s1n;
            float r = sigf(g0 + br + ar);
            float z = sigf(g1 + bz + az);
            float n = tanhfast(g2 + r * (bn + an));
            h_cur = n + z * (h_cur - n);
            if (writer) DST[hsel] = h_cur;
            asm volatile("s_waitcnt lgkmcnt(0)\n\ts_barrier" ::: "memory");
        };

        auto superstep = [&](int TL, float4& S0, float4& S1, float4& S2) {
            float l00 = S0.x, l01 = S0.y, l02 = S0.z, l03 = S0.w;
            float l10 = S1.x, l11 = S1.y, l12 = S1.z, l13 = S1.w;
            float l20 = S2.x, l21 = S2.y, l22 = S2.z, l23 = S2.w;
            int tpf = TL + 8; if (tpf > ct - 4) tpf = ct - 4;
            S0 = *(const float4*)(gp0 + tpf);
            S1 = *(const float4*)(gp1 + tpf);
            S2 = *(const float4*)(gp2 + tpf);
            dostep(l00, l10, l20, hsA, hsB);
            dostep(l01, l11, l21, hsB, hsA);
            dostep(l02, l12, l22, hsA, hsB);
            dostep(l03, l13, l23, hsB, hsA);
        };

        int tl = 0;
        for (; tl + 8 <= ct; tl += 8) {
            superstep(tl, A0, A1, A2);
            superstep(tl + 4, B0, B1, B2);
        }
        if (tl < ct) superstep(tl, A0, A1, A2);   // ct is a multiple of 4

        if (!last) {
            if (writer) h_state[b * H + jsel] = h_cur;
            return;
        }

        // ---- backward single step (h0 = 0) + MLP head ----
        if (tid < NI) xb_s[tid] = x[((size_t)b * T + (T - 1)) * NI + tid];
        if (writer) last_s[jsel] = h_cur;  // forward final hidden
        __syncthreads();

        if (tid < G) {
            const float4* wbr = (const float4*)(w_ih_b + (size_t)tid * NI);
            const float4* xv = (const float4*)xb_s;
            float a0 = 0.f, a1 = 0.f, a2 = 0.f, a3 = 0.f;
#pragma unroll
            for (int i = 0; i < 20; ++i) {
                float4 wv = wbr[i]; float4 x4 = xv[i];
                a0 = fmaf(wv.x, x4.x, a0); a1 = fmaf(wv.y, x4.y, a1);
                a2 = fmaf(wv.z, x4.z, a2); a3 = fmaf(wv.w, x4.w, a3);
            }
            tail_gx[tid] = b_ih_b[tid] + ((a0 + a1) + (a2 + a3));
        }
        __syncthreads();

        if (tid < H) {
            float r = sigf(tail_gx[tid] + b_hh_b[tid]);
            float z = sigf(tail_gx[tid + H] + b_hh_b[tid + H]);
            float n = tanhfast(tail_gx[tid + 2 * H] + r * b_hh_b[tid + 2 * H]);
            last_s[H + tid] = (1.f - z) * n;  // + z*0
        }
        __syncthreads();

        if (tid < 64) {
            const float4* w1r = (const float4*)(w1 + (size_t)tid * 2 * H);
            const float4* lv = (const float4*)last_s;
            float a0 = 0.f, a1 = 0.f, a2 = 0.f, a3 = 0.f;
#pragma unroll
            for (int i = 0; i < 64; ++i) {
                float4 wv = w1r[i]; float4 l4 = lv[i];
                a0 = fmaf(wv.x, l4.x, a0); a1 = fmaf(wv.y, l4.y, a1);
                a2 = fmaf(wv.z, l4.z, a2); a3 = fmaf(wv.w, l4.w, a3);
            }
            float v = b1[tid] + ((a0 + a1) + (a2 + a3));
            v = fmaxf(v, 0.f) * w2[tid];
#pragma unroll
            for (int off = 32; off > 0; off >>= 1) v += __shfl_down(v, off);
            if (tid == 0) out[b] = v + b2[0];
        }
        return;
    }

    // ================= GEMM ROLE (v3 logic, 512 threads, grid-stride over tile jobs) ======
    if (ct_write <= 0) return;
    {
        float* wT = smem;                 // [80][GT+2]
        float* xT = smem + WSZ;           // [80][NTT+4]; reused as out-tile
        float* bias_s = smem + WSZ + XSZ; // [GT]
        int ct = ct_write;
        int t0 = t0_write;
        int gb = blockIdx.x - scanBlocks;
        int ngb = gridDim.x - scanBlocks;
        int ttiles = (ct + NTT - 1) / NTT;
        int jobs = ttiles * (G / GT) * B;
        int gi = tid & 15;   // 4g block
        int ti = tid >> 4;   // 4t block, 0..31

        for (int job = gb; job < jobs; job += ngb) {
            int tile = job % ttiles;
            int rem = job / ttiles;
            int gy = rem % (G / GT);
            int b = rem / (G / GT);
            int g0b = gy * GT;
            int tt0 = tile * NTT;

            __syncthreads();   // protect previous job's LDS reads
            for (int i = tid; i < GT * 20; i += 512) {
                int g = i & (GT - 1);
                int kc = i >> 6;
                float4 v = *(const float4*)(w_ih + (size_t)(g0b + g) * NI + 4 * kc);
                wT[(4 * kc + 0) * (GT + 2) + g] = v.x; wT[(4 * kc + 1) * (GT + 2) + g] = v.y;
                wT[(4 * kc + 2) * (GT + 2) + g] = v.z; wT[(4 * kc + 3) * (GT + 2) + g] = v.w;
            }
            for (int i = tid; i < NTT * 20; i += 512) {
                int c = i & (NTT - 1);
                int kc = i >> 7;
                int tt = tt0 + c; if (tt > ct - 1) tt = ct - 1;
                float4 v = *(const float4*)(x + ((size_t)b * T + (size_t)(t0 + tt)) * NI + 4 * kc);
                xT[(4 * kc + 0) * (NTT + 4) + c] = v.x; xT[(4 * kc + 1) * (NTT + 4) + c] = v.y;
                xT[(4 * kc + 2) * (NTT + 4) + c] = v.z; xT[(4 * kc + 3) * (NTT + 4) + c] = v.w;
            }
            if (tid < GT) bias_s[tid] = b_ih[g0b + tid];
            __syncthreads();

            v2f acc[4][2];
#pragma unroll
            for (int r = 0; r < 4; ++r) { acc[r][0] = v2f{0.f, 0.f}; acc[r][1] = v2f{0.f, 0.f}; }

#pragma unroll 2
            for (int k = 0; k < 80; ++k) {
                const v2f* wv = (const v2f*)&wT[k * (GT + 2) + 4 * gi];
                v2f w01 = wv[0], w23 = wv[1];
                float4 x03 = *(const float4*)&xT[k * (NTT + 4) + 4 * ti];
                v2f xp0 = {x03.x, x03.y}, xp1 = {x03.z, x03.w};
                float wr[4] = {w01.x, w01.y, w23.x, w23.y};
#pragma unroll
                for (int r = 0; r < 4; ++r) {
                    v2f ws = {wr[r], wr[r]};
                    acc[r][0] = pkfma(ws, xp0, acc[r][0]);
                    acc[r][1] = pkfma(ws, xp1, acc[r][1]);
                }
            }
            __syncthreads();   // xT reads done; reuse as output tile

#pragma unroll
            for (int r = 0; r < 4; ++r) {
                float bias = bias_s[4 * gi + r];
                float2 o0, o1;
                o0.x = acc[r][0].x + bias; o0.y = acc[r][0].y + bias;
                o1.x = acc[r][1].x + bias; o1.y = acc[r][1].y + bias;
                *(float2*)&xT[(4 * gi + r) * (NTT + 4) + 4 * ti]     = o0;
                *(float2*)&xT[(4 * gi + r) * (NTT + 4) + 4 * ti + 2] = o1;
            }
            __syncthreads();

            // coalesced copy-out: 2048 float4
            for (int i = tid; i < GT * (NTT / 4); i += 512) {
                int row = i >> 5;          // /32 float4 per row
                int col = i & 31;
                int t = tt0 + 4 * col;
                if (t < ct) {
                    float4 v = *(const float4*)&xT[row * (NTT + 4) + 4 * col];
                    *(float4*)(gx_write + ((size_t)b * G + g0b + row) * ct + t) = v;
                }
            }
        }
    }
}

extern "C" void kernel_launch(void* const* d_in, const int* in_sizes, int n_in,
                              void* d_out, int out_size, void* d_ws, size_t ws_size,
                              hipStream_t stream) {
    (void)in_sizes; (void)n_in; (void)out_size;
    const float* x      = (const float*)d_in[0];
    const float* w_ih_f = (const float*)d_in[1];
    const float* w_hh_f = (const float*)d_in[2];
    const float* b_ih_f = (const float*)d_in[3];
    const float* b_hh_f = (const float*)d_in[4];
    const float* w_ih_b = (const float*)d_in[5];
    const float* w_hh_b = (const float*)d_in[6];  // unused: h0=0 makes gh_b = b_hh_b
    const float* b_ih_b = (const float*)d_in[7];
    const float* b_hh_b = (const float*)d_in[8];
    const float* w1     = (const float*)d_in[9];
    const float* b1     = (const float*)d_in[10];
    const float* w2     = (const float*)d_in[11];
    const float* b2     = (const float*)d_in[12];
    (void)w_hh_b;
    float* out = (float*)d_out;

    float* h_state = (float*)d_ws;                 // B*H floats
    float* buf0 = h_state + B * H;
    size_t hbytes = (size_t)B * H * sizeof(float);
    size_t avail = ws_size > hbytes ? ws_size - hbytes : 0;

    // chunk size: 376 (nc=4) if two buffers fit; else largest mult-of-4 that fits two buffers
    long long chunk = 376;
    size_t per = (size_t)B * G * sizeof(float);
    if (avail < 2 * per * (size_t)chunk) {
        long long c = (long long)(avail / (2 * per)) & ~3LL;
        chunk = c;
    }
    if (chunk > T) chunk = T;
    if (chunk < 4) chunk = 4;   // ws assumed to at least fit this (held 295MB historically)

    float* bufs[2] = { buf0, buf0 + (size_t)B * G * (size_t)chunk };

    // prologue: all 256 blocks produce chunk 0
    int cs0 = (T < (int)chunk) ? T : (int)chunk;
    fused_kernel<<<dim3(256), dim3(512), 0, stream>>>(
        x, w_ih_f, b_ih_f,
        nullptr, 0, 0, 0,
        bufs[0], 0, cs0,
        w_hh_f, b_hh_f, h_state,
        w_ih_b, b_ih_b, b_hh_b, w1, b1, w2, b2, out);

    int i = 0;
    for (int t0 = 0; t0 < T; ++i) {
        int cs = (T - t0 < (int)chunk) ? (T - t0) : (int)chunk;
        int nt0 = t0 + cs;
        int csn = (nt0 < T) ? ((T - nt0 < (int)chunk) ? (T - nt0) : (int)chunk) : 0;
        fused_kernel<<<dim3(256), dim3(512), 0, stream>>>(
            x, w_ih_f, b_ih_f,
            bufs[i & 1], cs, (t0 == 0) ? 1 : 0, (nt0 >= T) ? 1 : 0,
            bufs[(i + 1) & 1], nt0, csn,
            w_hh_f, b_hh_f, h_state,
            w_ih_b, b_ih_b, b_hh_b, w1, b1, w2, b2, out);
        t0 = nt0;
    }
}